// Round 12
// baseline (200.781 us; speedup 1.0000x reference)
//
#include <hip/hip_runtime.h>

#define N_NODES 16384
#define F_IN    128
#define F_HID   256
#define F_OUT   128
#define LN_EPS  1e-5f
#define CAP     96    // ELL slots/row; P(deg>=96 | Poisson(32)) ~ 1e-18/row
#define H0STR   136   // LDS h0 stride (ushorts)
#define H1STR   264   // LDS post-LN stride (ushorts)
#define REPSTR  132   // LDS C2 repack stride (ushorts)
#define PLANEU  (N_NODES * 32)   // uints per 64-feature plane (128 B/node)

typedef __attribute__((ext_vector_type(8))) short bf16x8;
typedef __attribute__((ext_vector_type(4))) float f32x4;
typedef __attribute__((ext_vector_type(4))) int   i32x4;
typedef __attribute__((ext_vector_type(4))) unsigned u32x4;

__device__ __forceinline__ unsigned short bf16rne(float f) {
    unsigned u = __float_as_uint(f);
    unsigned r = (u + 0x7fffu + ((u >> 16) & 1u)) >> 16;   // round-to-nearest-even
    return (unsigned short)r;
}
__device__ __forceinline__ float bf_lo(unsigned v) { return __uint_as_float(v << 16); }
__device__ __forceinline__ float bf_hi(unsigned v) { return __uint_as_float(v & 0xffff0000u); }

// ---------------------------------------------------------------------------
// Tiny prologue: zero cur (blocks 0..63) + detect int64 vs int32 edge_index.
__global__ void pre_small_kernel(int* __restrict__ cur, const unsigned* __restrict__ ei,
                                 int* __restrict__ mode) {
    int b = blockIdx.x, t = threadIdx.x;
    if (b < 64) {
        cur[b * 256 + t] = 0;
    } else {
        __shared__ int nz;
        if (t == 0) nz = 0;
        __syncthreads();
        for (int it = 0; it < 4; ++it) {
            int idx = 2 * (t + it * 256) + 1;
            if (ei[idx] != 0u) nz = 1;        // benign race
        }
        __syncthreads();
        if (t == 0) *mode = (nz == 0) ? 1 : 0;  // 1 => int64
    }
}

// ---------------------------------------------------------------------------
// Fused prep: ELL fill + x fp32->bf16 (PLANE layout: feats [0,64) then
// [64,128); 2.1 MB per plane -> one plane fits a 4 MiB XCD L2 during the
// per-plane gather kernels) + W1/W2 transpose-to-bf16.
__global__ void prep_fill_kernel(const void* __restrict__ ei, const int* __restrict__ mode,
                                 int* __restrict__ cur, int2* __restrict__ ed, int E, int nF,
                                 const float* __restrict__ x, unsigned short* __restrict__ xb,
                                 const float* __restrict__ W1, unsigned short* __restrict__ W1t,
                                 const float* __restrict__ W2, unsigned short* __restrict__ W2t) {
    int b = blockIdx.x, t = threadIdx.x;
    if (b < nF) {
        int base = b * 1024 + t;
        int m = *mode;
#pragma unroll
        for (int u = 0; u < 4; ++u) {
            int e = base + u * 256;
            if (e >= E) continue;
            int r, c;
            if (m) {
                const long long* p = (const long long*)ei;
                r = (int)p[e]; c = (int)p[e + E];
            } else {
                const int* p = (const int*)ei;
                r = p[e]; c = p[e + E];
            }
            if (((unsigned)r | (unsigned)c) >= N_NODES) continue;   // replay-safety guard
            int pos = atomicAdd(&cur[r], 1);
            if (pos < CAP) ed[r * CAP + pos] = make_int2(c, e);
        }
    } else if (b < nF + 2048) {
        int i = ((b - nF) * 256 + t) * 4;     // source feat-quad (row-major)
        float4 v = *(const float4*)&x[i];
        ushort4 o;
        o.x = bf16rne(v.x); o.y = bf16rne(v.y); o.z = bf16rne(v.z); o.w = bf16rne(v.w);
        int n = i >> 7, f = i & 127;
        int p = f >> 6, fo = f & 63;          // plane, offset-in-plane
        *(ushort4*)&xb[(size_t)p * (N_NODES * 64) + n * 64 + fo] = o;
    } else if (b < nF + 2176) {
        int id = (b - nF - 2048) * 256 + t;   // [0, 32768)
        int n = id >> 7, k = id & 127;
        W1t[id] = bf16rne(W1[(size_t)k * F_HID + n]);
    } else {
        int id = (b - nF - 2176) * 256 + t;   // [0, 32768)
        int n = id >> 8, k = id & 255;
        W2t[id] = bf16rne(W2[(size_t)k * F_OUT + n]);
    }
}

// ---------------------------------------------------------------------------
// Octet-wave plane gather core (8 lanes = 1 neighbor's 64-feat plane row,
// 8 neighbors/load-slot, 32 neighbors per 4-load batch; octs combined via
// shfl_xor 8,16,32). Used by agg_p0 / agg_p1 / spmm2_p below.
// ---------------------------------------------------------------------------
// agg plane 0: stage {col,eid} -> dedupe (batched 16-wide, last-edge-wins) ->
// ed={col,w} writeback + invdeg + cur clamp -> gather x plane0 -> g0 bf16.
__launch_bounds__(1024, 8)
__global__ void agg_p0_kernel(const float* __restrict__ ew, int* __restrict__ cur,
                              int2* __restrict__ ed, float* __restrict__ invdeg,
                              const unsigned* __restrict__ xb,
                              unsigned short* __restrict__ g0) {
    __shared__ int   scol[16][CAP];             // 6 KB
    __shared__ int   seid[16][CAP];             // 6 KB
    __shared__ float sw[16][CAP];               // 6 KB
    int t = threadIdx.x, wave = t >> 6, lane = t & 63;
    int qo = lane >> 3, ql8 = lane & 7;
    int r = blockIdx.x * 16 + wave;

    int d = cur[r];
    if (d > CAP) d = CAP;
    int dpad = (d + 15) & ~15;
    int2* row = ed + (size_t)r * CAP;
    for (int i = lane; i < d; i += 64) {
        int2 e = row[i];
        scol[wave][i] = e.x;
        seid[wave][i] = e.y;
    }
    for (int i = d + lane; i < dpad; i += 64) {   // sentinel pad
        scol[wave][i] = -2;
        seid[wave][i] = 0;
    }
    asm volatile("s_waitcnt lgkmcnt(0)" ::: "memory");

    float wsum = 0.0f;
    for (int i = lane; i < d; i += 64) {
        int myc = scol[wave][i], mye = seid[wave][i];
        bool kill = false;
        for (int jb = 0; jb < dpad; jb += 16) {
            const int* cb = &scol[wave][jb];
            const int* eb = &seid[wave][jb];
            i32x4 c0 = *(const i32x4*)(cb);
            i32x4 c1 = *(const i32x4*)(cb + 4);
            i32x4 c2 = *(const i32x4*)(cb + 8);
            i32x4 c3 = *(const i32x4*)(cb + 12);
            i32x4 e0 = *(const i32x4*)(eb);
            i32x4 e1 = *(const i32x4*)(eb + 4);
            i32x4 e2 = *(const i32x4*)(eb + 8);
            i32x4 e3 = *(const i32x4*)(eb + 12);
            kill |= (c0.x == myc && e0.x > mye);
            kill |= (c0.y == myc && e0.y > mye);
            kill |= (c0.z == myc && e0.z > mye);
            kill |= (c0.w == myc && e0.w > mye);
            kill |= (c1.x == myc && e1.x > mye);
            kill |= (c1.y == myc && e1.y > mye);
            kill |= (c1.z == myc && e1.z > mye);
            kill |= (c1.w == myc && e1.w > mye);
            kill |= (c2.x == myc && e2.x > mye);
            kill |= (c2.y == myc && e2.y > mye);
            kill |= (c2.z == myc && e2.z > mye);
            kill |= (c2.w == myc && e2.w > mye);
            kill |= (c3.x == myc && e3.x > mye);
            kill |= (c3.y == myc && e3.y > mye);
            kill |= (c3.z == myc && e3.z > mye);
            kill |= (c3.w == myc && e3.w > mye);
        }
        float w = kill ? 0.0f : ew[mye];
        sw[wave][i] = w;
        row[i] = make_int2(myc, __float_as_int(w));   // {col, weight} for later kernels
        wsum += w;
    }
    asm volatile("s_waitcnt lgkmcnt(0)" ::: "memory");
    for (int off = 32; off; off >>= 1) wsum += __shfl_xor(wsum, off, 64);
    float inv = 1.0f / (1.0f + wsum);                // +1 self-loop
    if (lane == 0) { invdeg[r] = inv; cur[r] = d; }

    // ---- plane-0 gather ----
    const u32x4* xp4 = (const u32x4*)xb;             // plane 0; node row = 8 u32x4
    float a[8] = {0, 0, 0, 0, 0, 0, 0, 0};
    int j = 0;
    for (; j + 32 <= d; j += 32) {
        int c[4]; float w[4]; u32x4 v[4];
#pragma unroll
        for (int u = 0; u < 4; ++u) {
            int n = j + u * 8 + qo;
            c[u] = scol[wave][n];
            w[u] = sw[wave][n];
        }
#pragma unroll
        for (int u = 0; u < 4; ++u) v[u] = xp4[(size_t)c[u] * 8 + ql8];
#pragma unroll
        for (int u = 0; u < 4; ++u)
#pragma unroll
            for (int m = 0; m < 4; ++m) {
                a[2 * m]     += w[u] * bf_lo(v[u][m]);
                a[2 * m + 1] += w[u] * bf_hi(v[u][m]);
            }
    }
    for (; j < d; j += 8) {                           // 8-neighbor tail slots
        int rem = d - j;
        int n = j + (qo < rem ? qo : 0);
        float w = (qo < rem) ? sw[wave][n] : 0.0f;
        int c = scol[wave][n];
        u32x4 v = xp4[(size_t)c * 8 + ql8];
#pragma unroll
        for (int m = 0; m < 4; ++m) {
            a[2 * m]     += w * bf_lo(v[m]);
            a[2 * m + 1] += w * bf_hi(v[m]);
        }
    }
#pragma unroll
    for (int k = 0; k < 8; ++k) {                    // combine the 8 octs
        a[k] += __shfl_xor(a[k], 8, 64);
        a[k] += __shfl_xor(a[k], 16, 64);
        a[k] += __shfl_xor(a[k], 32, 64);
    }
    if (qo == 0) {                                   // + self, scale, bf16
        u32x4 sv = xp4[(size_t)r * 8 + ql8];
        u32x4 o;
#pragma unroll
        for (int m = 0; m < 4; ++m) {
            float lo = (a[2 * m]     + bf_lo(sv[m])) * inv;
            float hi = (a[2 * m + 1] + bf_hi(sv[m])) * inv;
            o[m] = ((unsigned)bf16rne(hi) << 16) | (unsigned)bf16rne(lo);
        }
        *(u32x4*)&g0[(size_t)r * 64 + ql8 * 8] = o;  // 16 B aligned
    }
}

// ---------------------------------------------------------------------------
// agg plane 1: stage {col,w} (post-dedupe ed), gather x plane1 -> g1 bf16.
__launch_bounds__(1024, 8)
__global__ void agg_p1_kernel(const int* __restrict__ cur, const int2* __restrict__ ed,
                              const float* __restrict__ invdeg,
                              const unsigned* __restrict__ xb,
                              unsigned short* __restrict__ g1) {
    __shared__ int   scol[16][CAP];
    __shared__ float sw[16][CAP];
    int t = threadIdx.x, wave = t >> 6, lane = t & 63;
    int qo = lane >> 3, ql8 = lane & 7;
    int r = blockIdx.x * 16 + wave;
    const int2* row = ed + (size_t)r * CAP;
    int d = cur[r];
    if (d > CAP) d = CAP;
    for (int i = lane; i < d; i += 64) {
        int2 e = row[i];
        scol[wave][i] = e.x;
        sw[wave][i] = __int_as_float(e.y);
    }
    asm volatile("s_waitcnt lgkmcnt(0)" ::: "memory");
    float inv = invdeg[r];

    const u32x4* xp4 = (const u32x4*)(xb + PLANEU);  // plane 1
    float a[8] = {0, 0, 0, 0, 0, 0, 0, 0};
    int j = 0;
    for (; j + 32 <= d; j += 32) {
        int c[4]; float w[4]; u32x4 v[4];
#pragma unroll
        for (int u = 0; u < 4; ++u) {
            int n = j + u * 8 + qo;
            c[u] = scol[wave][n];
            w[u] = sw[wave][n];
        }
#pragma unroll
        for (int u = 0; u < 4; ++u) v[u] = xp4[(size_t)c[u] * 8 + ql8];
#pragma unroll
        for (int u = 0; u < 4; ++u)
#pragma unroll
            for (int m = 0; m < 4; ++m) {
                a[2 * m]     += w[u] * bf_lo(v[u][m]);
                a[2 * m + 1] += w[u] * bf_hi(v[u][m]);
            }
    }
    for (; j < d; j += 8) {
        int rem = d - j;
        int n = j + (qo < rem ? qo : 0);
        float w = (qo < rem) ? sw[wave][n] : 0.0f;
        int c = scol[wave][n];
        u32x4 v = xp4[(size_t)c * 8 + ql8];
#pragma unroll
        for (int m = 0; m < 4; ++m) {
            a[2 * m]     += w * bf_lo(v[m]);
            a[2 * m + 1] += w * bf_hi(v[m]);
        }
    }
#pragma unroll
    for (int k = 0; k < 8; ++k) {
        a[k] += __shfl_xor(a[k], 8, 64);
        a[k] += __shfl_xor(a[k], 16, 64);
        a[k] += __shfl_xor(a[k], 32, 64);
    }
    if (qo == 0) {
        u32x4 sv = xp4[(size_t)r * 8 + ql8];
        u32x4 o;
#pragma unroll
        for (int m = 0; m < 4; ++m) {
            float lo = (a[2 * m]     + bf_lo(sv[m])) * inv;
            float hi = (a[2 * m + 1] + bf_hi(sv[m])) * inv;
            o[m] = ((unsigned)bf16rne(hi) << 16) | (unsigned)bf16rne(lo);
        }
        *(u32x4*)&g1[(size_t)r * 64 + ql8 * 8] = o;
    }
}

// ---------------------------------------------------------------------------
// MLP: h2 = relu(LN(h0 @ W1 + b1)) @ W2 in bf16 (b2 added in spmm2).
// 16 rows/block, 16 waves. h0 staged from g0/g1 planes into LDS.
__launch_bounds__(1024, 8)
__global__ void mlp_kernel(const unsigned short* __restrict__ g0,
                           const unsigned short* __restrict__ g1,
                           const unsigned short* __restrict__ W1t,
                           const unsigned short* __restrict__ W2t,
                           const float* __restrict__ b1,
                           const float* __restrict__ ln_g, const float* __restrict__ ln_b,
                           unsigned short* __restrict__ h2b) {
    __shared__ unsigned short H0[16 * H0STR];   // 4.25 KB; reused as C2 repack
    __shared__ unsigned short H1[16 * H1STR];   // 8.25 KB
    __shared__ float red[2][16][16];            // 2 KB
    int t = threadIdx.x, wave = t >> 6, lane = t & 63;
    int lnid = lane & 15, quad = lane >> 4;
    int Rbase = blockIdx.x * 16;

    // stage h0: 16 rows x 128 feats (512 ushort4; feats p*64+fo)
    if (t < 512) {
        int m = t >> 5, cg = t & 31;
        int p = cg >> 4, fo = (cg & 15) * 4;
        const unsigned short* src = (p ? g1 : g0) + (size_t)(Rbase + m) * 64 + fo;
        *(ushort4*)&H0[m * H0STR + p * 64 + fo] = *(const ushort4*)src;
    }
    __syncthreads();

    // ---- stage A: C1[16x256] = h0 @ W1, K=128; wave handles ct = wave ----
    bf16x8 afr[4];
#pragma unroll
    for (int ch = 0; ch < 4; ++ch)
        afr[ch] = *(const bf16x8*)&H0[lnid * H0STR + ch * 32 + quad * 8];
    f32x4 acc = {0.0f, 0.0f, 0.0f, 0.0f};
    {
        const unsigned short* wrow = &W1t[(size_t)(wave * 16 + lnid) * F_IN];
#pragma unroll
        for (int ch = 0; ch < 4; ++ch) {
            bf16x8 b = *(const bf16x8*)&wrow[ch * 32 + quad * 8];
            acc = __builtin_amdgcn_mfma_f32_16x16x32_bf16(afr[ch], b, acc, 0, 0, 0);
        }
    }
    float s[4], q[4];
    {
        float bv = b1[wave * 16 + lnid];
#pragma unroll
        for (int rr = 0; rr < 4; ++rr) {
            float v = acc[rr] + bv;
            acc[rr] = v;
            s[rr] = v; q[rr] = v * v;
        }
    }
#pragma unroll
    for (int rr = 0; rr < 4; ++rr)
        for (int off = 1; off < 16; off <<= 1) {
            s[rr] += __shfl_xor(s[rr], off, 64);
            q[rr] += __shfl_xor(q[rr], off, 64);
        }
    if (lnid == 0) {
#pragma unroll
        for (int rr = 0; rr < 4; ++rr) {
            red[0][wave][quad * 4 + rr] = s[rr];
            red[1][wave][quad * 4 + rr] = q[rr];
        }
    }
    __syncthreads();
    float mean[4], rinv[4];
#pragma unroll
    for (int rr = 0; rr < 4; ++rr) {
        int rowi = quad * 4 + rr;
        float S = 0.0f, Q = 0.0f;
#pragma unroll
        for (int w2 = 0; w2 < 16; ++w2) { S += red[0][w2][rowi]; Q += red[1][w2][rowi]; }
        mean[rr] = S * (1.0f / F_HID);
        float var = Q * (1.0f / F_HID) - mean[rr] * mean[rr];
        rinv[rr] = rsqrtf(var + LN_EPS);
    }
    {
        int c = wave * 16 + lnid;
        float g = ln_g[c], bb = ln_b[c];
#pragma unroll
        for (int rr = 0; rr < 4; ++rr) {
            float v = fmaxf((acc[rr] - mean[rr]) * rinv[rr] * g + bb, 0.0f);
            H1[(quad * 4 + rr) * H1STR + c] = bf16rne(v);
        }
    }
    __syncthreads();

    // ---- stage B: C2[16x128] = H1 @ W2, K=256; waves 0-7, ct = wave ----
    unsigned short* rep = H0;
    if (wave < 8) {
        bf16x8 a2[8];
#pragma unroll
        for (int ch = 0; ch < 8; ++ch)
            a2[ch] = *(const bf16x8*)&H1[lnid * H1STR + ch * 32 + quad * 8];
        f32x4 c2 = {0.0f, 0.0f, 0.0f, 0.0f};
        const unsigned short* wrow = &W2t[(size_t)(wave * 16 + lnid) * F_HID];
#pragma unroll
        for (int ch = 0; ch < 8; ++ch) {
            bf16x8 b = *(const bf16x8*)&wrow[ch * 32 + quad * 8];
            c2 = __builtin_amdgcn_mfma_f32_16x16x32_bf16(a2[ch], b, c2, 0, 0, 0);
        }
#pragma unroll
        for (int rr = 0; rr < 4; ++rr)
            rep[(quad * 4 + rr) * REPSTR + wave * 16 + lnid] = bf16rne(c2[rr]);
    }
    __syncthreads();

    // plane-layout store: h2b[p][node][64]
    if (t < 512) {
        int m = t >> 5, cg = t & 31;
        int p = cg >> 4, fo = (cg & 15) * 4;
        *(ushort4*)&h2b[(size_t)p * (N_NODES * 64) + (size_t)(Rbase + m) * 64 + fo] =
            *(const ushort4*)&rep[m * REPSTR + cg * 4];
    }
}

// ---------------------------------------------------------------------------
// spmm2 plane kernel: out[:, plane*64 .. +64) = invdeg * (A+I) h2_plane + b2.
// Octet-wave gathers from a 2.1 MB plane (L2-resident per XCD).
__launch_bounds__(1024, 8)
__global__ void spmm2_p_kernel(const unsigned* __restrict__ h2u, const int* __restrict__ cur,
                               const int2* __restrict__ ed, const float* __restrict__ invdeg,
                               const float* __restrict__ bias, float* __restrict__ outp,
                               int plane) {
    __shared__ int   scol[16][CAP];
    __shared__ float sw[16][CAP];
    int t = threadIdx.x, wave = t >> 6, lane = t & 63;
    int qo = lane >> 3, ql8 = lane & 7;
    int r = blockIdx.x * 16 + wave;
    const int2* row = ed + (size_t)r * CAP;
    int d = cur[r];
    if (d > CAP) d = CAP;
    for (int i = lane; i < d; i += 64) {
        int2 e = row[i];
        scol[wave][i] = e.x;
        sw[wave][i] = __int_as_float(e.y);
    }
    asm volatile("s_waitcnt lgkmcnt(0)" ::: "memory");

    const u32x4* xp4 = (const u32x4*)(h2u + (size_t)plane * PLANEU);
    float a[8] = {0, 0, 0, 0, 0, 0, 0, 0};
    int j = 0;
    for (; j + 32 <= d; j += 32) {
        int c[4]; float w[4]; u32x4 v[4];
#pragma unroll
        for (int u = 0; u < 4; ++u) {
            int n = j + u * 8 + qo;
            c[u] = scol[wave][n];
            w[u] = sw[wave][n];
        }
#pragma unroll
        for (int u = 0; u < 4; ++u) v[u] = xp4[(size_t)c[u] * 8 + ql8];
#pragma unroll
        for (int u = 0; u < 4; ++u)
#pragma unroll
            for (int m = 0; m < 4; ++m) {
                a[2 * m]     += w[u] * bf_lo(v[u][m]);
                a[2 * m + 1] += w[u] * bf_hi(v[u][m]);
            }
    }
    for (; j < d; j += 8) {
        int rem = d - j;
        int n = j + (qo < rem ? qo : 0);
        float w = (qo < rem) ? sw[wave][n] : 0.0f;
        int c = scol[wave][n];
        u32x4 v = xp4[(size_t)c * 8 + ql8];
#pragma unroll
        for (int m = 0; m < 4; ++m) {
            a[2 * m]     += w * bf_lo(v[m]);
            a[2 * m + 1] += w * bf_hi(v[m]);
        }
    }
#pragma unroll
    for (int k = 0; k < 8; ++k) {
        a[k] += __shfl_xor(a[k], 8, 64);
        a[k] += __shfl_xor(a[k], 16, 64);
        a[k] += __shfl_xor(a[k], 32, 64);
    }
    if (qo == 0) {                                   // + self, scale, bias, store
        float inv = invdeg[r];
        u32x4 sv = xp4[(size_t)r * 8 + ql8];
        int f = plane * 64 + ql8 * 8;
        f32x4 o0, o1;
#pragma unroll
        for (int m = 0; m < 2; ++m) {
            o0[2 * m]     = (a[2 * m]     + bf_lo(sv[m])) * inv + bias[f + 2 * m];
            o0[2 * m + 1] = (a[2 * m + 1] + bf_hi(sv[m])) * inv + bias[f + 2 * m + 1];
        }
#pragma unroll
        for (int m = 2; m < 4; ++m) {
            o1[2 * m - 4] = (a[2 * m]     + bf_lo(sv[m])) * inv + bias[f + 2 * m];
            o1[2 * m - 3] = (a[2 * m + 1] + bf_hi(sv[m])) * inv + bias[f + 2 * m + 1];
        }
        *(f32x4*)&outp[(size_t)r * F_OUT + f]     = o0;
        *(f32x4*)&outp[(size_t)r * F_OUT + f + 4] = o1;
    }
}

// ---------------------------------------------------------------------------
extern "C" void kernel_launch(void* const* d_in, const int* in_sizes, int n_in,
                              void* d_out, int out_size, void* d_ws, size_t ws_size,
                              hipStream_t stream) {
    const float* x   = (const float*)d_in[0];
    const void*  ei  = d_in[1];
    const float* ew  = (const float*)d_in[2];
    const float* W1  = (const float*)d_in[3];
    const float* b1  = (const float*)d_in[4];
    const float* W2  = (const float*)d_in[5];
    const float* b2  = (const float*)d_in[6];
    const float* lng = (const float*)d_in[7];
    const float* lnb = (const float*)d_in[8];
    float* out = (float*)d_out;
    int E = in_sizes[2];

    char* w = (char*)d_ws;
    size_t off = 0;
    auto take = [&](size_t bytes) -> char* {
        char* p = w + off;
        off += (bytes + 255) & ~(size_t)255;
        return p;
    };
    int*   cur    = (int*)take((size_t)N_NODES * 4);
    float* invdeg = (float*)take((size_t)N_NODES * 4);
    int2*  ed     = (int2*)take((size_t)N_NODES * CAP * 8);
    unsigned short* xb  = (unsigned short*)take((size_t)N_NODES * F_IN * 2);
    unsigned short* h2b = (unsigned short*)take((size_t)N_NODES * F_OUT * 2);
    unsigned short* g0  = (unsigned short*)take((size_t)N_NODES * 64 * 2);
    unsigned short* g1  = (unsigned short*)take((size_t)N_NODES * 64 * 2);
    unsigned short* W1t = (unsigned short*)take((size_t)F_IN * F_HID * 2);
    unsigned short* W2t = (unsigned short*)take((size_t)F_HID * F_OUT * 2);
    int*   mode   = (int*)take(4);

    int nF = (E + 1023) / 1024;
    pre_small_kernel<<<65, 256, 0, stream>>>(cur, (const unsigned*)ei, mode);
    prep_fill_kernel<<<nF + 2304, 256, 0, stream>>>(ei, mode, cur, ed, E, nF,
                                                    x, xb, W1, W1t, W2, W2t);
    // plane-split aggregation: per-launch gather working set = 2.1 MB (L2-fit)
    agg_p0_kernel<<<N_NODES / 16, 1024, 0, stream>>>(ew, cur, ed, invdeg,
                                                     (const unsigned*)xb, g0);
    agg_p1_kernel<<<N_NODES / 16, 1024, 0, stream>>>(cur, ed, invdeg,
                                                     (const unsigned*)xb, g1);
    // h2b = bf16( relu(LN(h0 W1 + b1)) W2 ), plane layout
    mlp_kernel<<<N_NODES / 16, 1024, 0, stream>>>(g0, g1, W1t, W2t, b1, lng, lnb, h2b);
    // out = D^-1 (A+I) h2 + b2, one feature plane per launch
    spmm2_p_kernel<<<N_NODES / 16, 1024, 0, stream>>>((const unsigned*)h2b, cur, ed,
                                                      invdeg, b2, out, 0);
    spmm2_p_kernel<<<N_NODES / 16, 1024, 0, stream>>>((const unsigned*)h2b, cur, ed,
                                                      invdeg, b2, out, 1);
}

// Round 13
// 186.262 us; speedup vs baseline: 1.0779x; 1.0779x over previous
//
#include <hip/hip_runtime.h>
#include <hip/hip_cooperative_groups.h>

namespace cg = cooperative_groups;

#define N_NODES 16384
#define F_IN    128
#define F_HID   256
#define F_OUT   128
#define LN_EPS  1e-5f
#define CAP     96    // ELL slots/row; P(deg>=96 | Poisson(32)) ~ 1e-18/row
#define H0STR   136   // LDS h0 stride (ushorts); 272 B -> 16B-aligned rows
#define H1STR   264   // LDS post-LN stride (ushorts)
#define REPSTR  132   // LDS C2 repack stride (ushorts)
#define NB      1024  // mega grid: 4 blocks/CU x 256 CU
#define NT      512   // 8 waves/block

typedef __attribute__((ext_vector_type(8))) short bf16x8;
typedef __attribute__((ext_vector_type(4))) float f32x4;
typedef __attribute__((ext_vector_type(4))) int   i32x4;
typedef __attribute__((ext_vector_type(4))) unsigned u32x4;

__device__ __forceinline__ unsigned short bf16rne(float f) {
    unsigned u = __float_as_uint(f);
    unsigned r = (u + 0x7fffu + ((u >> 16) & 1u)) >> 16;   // round-to-nearest-even
    return (unsigned short)r;
}
__device__ __forceinline__ float bf_lo(unsigned v) { return __uint_as_float(v << 16); }
__device__ __forceinline__ float bf_hi(unsigned v) { return __uint_as_float(v & 0xffff0000u); }

// Quarter-wave uint4 gather over LDS-resident {col,w}: 16 lanes cover one
// neighbor's 256B row; 4 quarters = 4 neighbors/load-slot. Accumulates into
// float a[8]; combines quarters via shfl_xor(16,32). Requires in scope:
// scol, sw (LDS [16][CAP]), qw, ql, a[8].
#define QGATHER(lr_, src4_, dd_)                                            \
    {                                                                       \
        int j_ = 0;                                                         \
        for (; j_ + 16 <= (dd_); j_ += 16) {                                \
            int c_[4]; float w_[4]; u32x4 v_[4];                            \
            _Pragma("unroll")                                               \
            for (int u_ = 0; u_ < 4; ++u_) {                                \
                int n_ = j_ + u_ * 4 + qw;                                  \
                c_[u_] = scol[lr_][n_];                                     \
                w_[u_] = sw[lr_][n_];                                       \
            }                                                               \
            _Pragma("unroll")                                               \
            for (int u_ = 0; u_ < 4; ++u_)                                  \
                v_[u_] = (src4_)[(size_t)c_[u_] * 16 + ql];                 \
            _Pragma("unroll")                                               \
            for (int u_ = 0; u_ < 4; ++u_)                                  \
                _Pragma("unroll")                                           \
                for (int m_ = 0; m_ < 4; ++m_) {                            \
                    a[2 * m_]     += w_[u_] * bf_lo(v_[u_][m_]);            \
                    a[2 * m_ + 1] += w_[u_] * bf_hi(v_[u_][m_]);            \
                }                                                           \
        }                                                                   \
        for (; j_ + 4 <= (dd_); j_ += 4) {                                  \
            int n_ = j_ + qw;                                               \
            int c_ = scol[lr_][n_]; float w_ = sw[lr_][n_];                 \
            u32x4 v_ = (src4_)[(size_t)c_ * 16 + ql];                       \
            _Pragma("unroll")                                               \
            for (int m_ = 0; m_ < 4; ++m_) {                                \
                a[2 * m_]     += w_ * bf_lo(v_[m_]);                        \
                a[2 * m_ + 1] += w_ * bf_hi(v_[m_]);                        \
            }                                                               \
        }                                                                   \
        int rem_ = (dd_) - j_;                                              \
        if (rem_ > 0) {                                                     \
            int n_ = j_ + (qw < rem_ ? qw : 0);                             \
            float w_ = (qw < rem_) ? sw[lr_][n_] : 0.0f;                    \
            int c_ = scol[lr_][n_];                                         \
            u32x4 v_ = (src4_)[(size_t)c_ * 16 + ql];                       \
            _Pragma("unroll")                                               \
            for (int m_ = 0; m_ < 4; ++m_) {                                \
                a[2 * m_]     += w_ * bf_lo(v_[m_]);                        \
                a[2 * m_ + 1] += w_ * bf_hi(v_[m_]);                        \
            }                                                               \
        }                                                                   \
        _Pragma("unroll")                                                   \
        for (int k_ = 0; k_ < 8; ++k_) {                                    \
            a[k_] += __shfl_xor(a[k_], 16, 64);                             \
            a[k_] += __shfl_xor(a[k_], 32, 64);                             \
        }                                                                   \
    }

// Batched 16-wide dedupe compare block (order-independent last-edge-wins).
#define KILL16(lr_, jb_)                                                    \
    {                                                                       \
        const int* cb = &scol[lr_][jb_];                                    \
        const int* eb = &seid[lr_][jb_];                                    \
        i32x4 c0 = *(const i32x4*)(cb);                                     \
        i32x4 c1 = *(const i32x4*)(cb + 4);                                 \
        i32x4 c2 = *(const i32x4*)(cb + 8);                                 \
        i32x4 c3 = *(const i32x4*)(cb + 12);                                \
        i32x4 e0 = *(const i32x4*)(eb);                                     \
        i32x4 e1 = *(const i32x4*)(eb + 4);                                 \
        i32x4 e2 = *(const i32x4*)(eb + 8);                                 \
        i32x4 e3 = *(const i32x4*)(eb + 12);                                \
        kill |= (c0.x == myc && e0.x > mye);                                \
        kill |= (c0.y == myc && e0.y > mye);                                \
        kill |= (c0.z == myc && e0.z > mye);                                \
        kill |= (c0.w == myc && e0.w > mye);                                \
        kill |= (c1.x == myc && e1.x > mye);                                \
        kill |= (c1.y == myc && e1.y > mye);                                \
        kill |= (c1.z == myc && e1.z > mye);                                \
        kill |= (c1.w == myc && e1.w > mye);                                \
        kill |= (c2.x == myc && e2.x > mye);                                \
        kill |= (c2.y == myc && e2.y > mye);                                \
        kill |= (c2.z == myc && e2.z > mye);                                \
        kill |= (c2.w == myc && e2.w > mye);                                \
        kill |= (c3.x == myc && e3.x > mye);                                \
        kill |= (c3.y == myc && e3.y > mye);                                \
        kill |= (c3.z == myc && e3.z > mye);                                \
        kill |= (c3.w == myc && e3.w > mye);                                \
    }

// ===========================================================================
// MEGA: one cooperative kernel, 1024 blocks x 512 thr (4 blocks/CU, 32 w/CU).
// P0 prep -> sync -> P1 fill -> sync -> P2 dedupe+gather+MLP -> sync -> P3
// spmm2 (reuses LDS-resident {col,w}; no ed writeback, no invdeg/cur stores).
// ===========================================================================
__launch_bounds__(NT, 8)
__global__ void gcn_mega(const void* __restrict__ ei, const float* __restrict__ ew,
                         const float* __restrict__ x,
                         const float* __restrict__ W1, const float* __restrict__ b1,
                         const float* __restrict__ W2, const float* __restrict__ b2,
                         const float* __restrict__ lng, const float* __restrict__ lnb,
                         int* __restrict__ cur, int2* __restrict__ ed,
                         unsigned short* __restrict__ xb, unsigned short* __restrict__ h2b,
                         unsigned short* __restrict__ W1t, unsigned short* __restrict__ W2t,
                         int* __restrict__ mode, float* __restrict__ out, int E) {
    __shared__ int   scol[16][CAP];             // 6 KB   (persists P2 -> P3)
    __shared__ int   seid[16][CAP];             // 6 KB
    __shared__ float sw[16][CAP];               // 6 KB   (persists P2 -> P3)
    __shared__ unsigned short H0[16 * H0STR];   // 4.25 KB; reused as C2 repack
    __shared__ unsigned short H1[16 * H1STR];   // 8.25 KB
    __shared__ float red[2][8][16];             // 1 KB
    __shared__ int   nzs;

    cg::grid_group grid = cg::this_grid();
    int t = threadIdx.x, b = blockIdx.x;
    int gtid = b * NT + t;
    int wave = t >> 6, lane = t & 63;
    int lnid = lane & 15, quad = lane >> 4;
    int qw = lane >> 4, ql = lane & 15;

    // ---- P0: prep (x->bf16 1 float4/thread; W transposes; cur zero; mode) ----
    {
        int i = gtid * 4;                        // 524288 float4 == NB*NT threads
        float4 v = *(const float4*)&x[i];
        ushort4 o;
        o.x = bf16rne(v.x); o.y = bf16rne(v.y); o.z = bf16rne(v.z); o.w = bf16rne(v.w);
        *(ushort4*)&xb[i] = o;
    }
    if (gtid < 32768) {
        int n = gtid >> 7, k = gtid & 127;
        W1t[gtid] = bf16rne(W1[(size_t)k * F_HID + n]);
    } else if (gtid < 65536) {
        int id = gtid - 32768;
        int n = id >> 8, k = id & 255;
        W2t[id] = bf16rne(W2[(size_t)k * F_OUT + n]);
    } else if (gtid < 65536 + N_NODES) {
        cur[gtid - 65536] = 0;
    }
    if (b == NB - 1) {                           // int64 vs int32 detect
        if (t == 0) nzs = 0;
        __syncthreads();
        const unsigned* eu = (const unsigned*)ei;
        for (int it = 0; it < 2; ++it) {
            int e = t + it * NT;
            if (e < E && eu[2 * e + 1] != 0u) nzs = 1;   // benign race
        }
        __syncthreads();
        if (t == 0) *mode = (nzs == 0) ? 1 : 0;
    }
    grid.sync();

    // ---- P1: ELL fill (grid-stride; 1 edge/thread at E = NB*NT) ----
    {
        int m = *mode;
        for (int e = gtid; e < E; e += NB * NT) {
            int r, c;
            if (m) {
                const long long* p = (const long long*)ei;
                r = (int)p[e]; c = (int)p[e + E];
            } else {
                const int* p = (const int*)ei;
                r = p[e]; c = p[e + E];
            }
            if (((unsigned)r | (unsigned)c) >= N_NODES) continue;   // replay-safety
            int pos = atomicAdd(&cur[r], 1);
            if (pos < CAP) ed[r * CAP + pos] = make_int2(c, e);
        }
    }
    grid.sync();

    // ---- P2: dedupe + gather (2 rows/wave) + block MLP on 16 rows ----
    int Rbase = b * 16;
    int dreg[2]; float invreg[2];
#pragma unroll 1
    for (int p = 0; p < 2; ++p) {
        int lr = wave + p * 8;
        int r = Rbase + lr;
        int d = cur[r];
        if (d > CAP) d = CAP;
        int dpad = (d + 15) & ~15;
        const int2* row = ed + (size_t)r * CAP;
        for (int i = lane; i < d; i += 64) {
            int2 e = row[i];
            scol[lr][i] = e.x;
            seid[lr][i] = e.y;
        }
        for (int i = d + lane; i < dpad; i += 64) {   // sentinel pad
            scol[lr][i] = -2;
            seid[lr][i] = 0;
        }
        asm volatile("s_waitcnt lgkmcnt(0)" ::: "memory");   // wave-local ordering

        float wsum = 0.0f;
        for (int i = lane; i < d; i += 64) {
            int myc = scol[lr][i], mye = seid[lr][i];
            bool kill = false;
            for (int jb = 0; jb < dpad; jb += 16) KILL16(lr, jb);
            float w = kill ? 0.0f : ew[mye];
            sw[lr][i] = w;                        // stays in LDS for P3 (no ed WB)
            wsum += w;
        }
        asm volatile("s_waitcnt lgkmcnt(0)" ::: "memory");
        for (int off = 32; off; off >>= 1) wsum += __shfl_xor(wsum, off, 64);
        float inv = 1.0f / (1.0f + wsum);         // +1 self-loop; >=1 so clip no-op
        dreg[p] = d;
        invreg[p] = inv;

        const u32x4* xb4 = (const u32x4*)xb;
        float a[8] = {0, 0, 0, 0, 0, 0, 0, 0};
        QGATHER(lr, xb4, d);
        if (qw == 0) {                            // + self, scale, bf16 -> H0
            u32x4 sv = xb4[(size_t)r * 16 + ql];
            u32x4 o;
#pragma unroll
            for (int m = 0; m < 4; ++m) {
                float lo = (a[2 * m]     + bf_lo(sv[m])) * inv;
                float hi = (a[2 * m + 1] + bf_hi(sv[m])) * inv;
                o[m] = ((unsigned)bf16rne(hi) << 16) | (unsigned)bf16rne(lo);
            }
            *(u32x4*)&H0[lr * H0STR + ql * 8] = o;
        }
    }
    __syncthreads();   // all 16 h0 rows staged

    // ---- MLP stage A: C1[16x256] = h0 @ W1, K=128; wave -> ct = wave, wave+8 ----
    {
        bf16x8 afr[4];
#pragma unroll
        for (int ch = 0; ch < 4; ++ch)
            afr[ch] = *(const bf16x8*)&H0[lnid * H0STR + ch * 32 + quad * 8];
        f32x4 acc[2];
#pragma unroll
        for (int p = 0; p < 2; ++p) {
            int ct = wave + p * 8;
            f32x4 c = {0.0f, 0.0f, 0.0f, 0.0f};
            const unsigned short* wrow = &W1t[(size_t)(ct * 16 + lnid) * F_IN];
#pragma unroll
            for (int ch = 0; ch < 4; ++ch) {
                bf16x8 bb = *(const bf16x8*)&wrow[ch * 32 + quad * 8];
                c = __builtin_amdgcn_mfma_f32_16x16x32_bf16(afr[ch], bb, c, 0, 0, 0);
            }
            acc[p] = c;
        }
        float s[4] = {0, 0, 0, 0}, q[4] = {0, 0, 0, 0};
#pragma unroll
        for (int p = 0; p < 2; ++p) {
            float bv = b1[(wave + p * 8) * 16 + lnid];
#pragma unroll
            for (int rr = 0; rr < 4; ++rr) {
                float v = acc[p][rr] + bv;
                acc[p][rr] = v;
                s[rr] += v; q[rr] += v * v;
            }
        }
#pragma unroll
        for (int rr = 0; rr < 4; ++rr)
            for (int off = 1; off < 16; off <<= 1) {
                s[rr] += __shfl_xor(s[rr], off, 64);
                q[rr] += __shfl_xor(q[rr], off, 64);
            }
        if (lnid == 0) {
#pragma unroll
            for (int rr = 0; rr < 4; ++rr) {
                red[0][wave][quad * 4 + rr] = s[rr];
                red[1][wave][quad * 4 + rr] = q[rr];
            }
        }
        __syncthreads();
        float mean[4], rinv[4];
#pragma unroll
        for (int rr = 0; rr < 4; ++rr) {
            int rowi = quad * 4 + rr;
            float S = 0.0f, Q = 0.0f;
#pragma unroll
            for (int w2 = 0; w2 < 8; ++w2) { S += red[0][w2][rowi]; Q += red[1][w2][rowi]; }
            mean[rr] = S * (1.0f / F_HID);
            float var = Q * (1.0f / F_HID) - mean[rr] * mean[rr];
            rinv[rr] = rsqrtf(var + LN_EPS);
        }
#pragma unroll
        for (int p = 0; p < 2; ++p) {
            int c = (wave + p * 8) * 16 + lnid;
            float g = lng[c], bb = lnb[c];
#pragma unroll
            for (int rr = 0; rr < 4; ++rr) {
                float v = fmaxf((acc[p][rr] - mean[rr]) * rinv[rr] * g + bb, 0.0f);
                H1[(quad * 4 + rr) * H1STR + c] = bf16rne(v);
            }
        }
    }
    __syncthreads();   // H1 complete; H0 a-frags consumed -> reusable as repack

    // ---- MLP stage B: C2[16x128] = H1 @ W2, K=256; wave = ct (8 tiles) ----
    unsigned short* rep = H0;
    {
        bf16x8 a2[8];
#pragma unroll
        for (int ch = 0; ch < 8; ++ch)
            a2[ch] = *(const bf16x8*)&H1[lnid * H1STR + ch * 32 + quad * 8];
        f32x4 c2 = {0.0f, 0.0f, 0.0f, 0.0f};
        const unsigned short* wrow = &W2t[(size_t)(wave * 16 + lnid) * F_HID];
#pragma unroll
        for (int ch = 0; ch < 8; ++ch) {
            bf16x8 bb = *(const bf16x8*)&wrow[ch * 32 + quad * 8];
            c2 = __builtin_amdgcn_mfma_f32_16x16x32_bf16(a2[ch], bb, c2, 0, 0, 0);
        }
#pragma unroll
        for (int rr = 0; rr < 4; ++rr)
            rep[(quad * 4 + rr) * REPSTR + wave * 16 + lnid] = bf16rne(c2[rr]);
    }
    __syncthreads();
    {   // coalesced h2b store: 512 ushort4, 1/thread
        int m = t >> 5, cgi = t & 31;
        *(ushort4*)&h2b[(size_t)(Rbase + m) * F_OUT + cgi * 4] =
            *(const ushort4*)&rep[m * REPSTR + cgi * 4];
    }
    grid.sync();   // h2b complete device-wide

    // ---- P3: spmm2 over the SAME rows, {col,w} still LDS-resident ----
    const u32x4* h24 = (const u32x4*)h2b;
#pragma unroll 1
    for (int p = 0; p < 2; ++p) {
        int lr = wave + p * 8;
        int r = Rbase + lr;
        int d = dreg[p];
        float inv = invreg[p];
        float a[8] = {0, 0, 0, 0, 0, 0, 0, 0};
        QGATHER(lr, h24, d);
        if (qw == 0) {                            // + self, scale, bias, store
            u32x4 sv = h24[(size_t)r * 16 + ql];
            int f = ql * 8;
            f32x4 o0, o1;
#pragma unroll
            for (int m = 0; m < 2; ++m) {
                o0[2 * m]     = (a[2 * m]     + bf_lo(sv[m])) * inv + b2[f + 2 * m];
                o0[2 * m + 1] = (a[2 * m + 1] + bf_hi(sv[m])) * inv + b2[f + 2 * m + 1];
            }
#pragma unroll
            for (int m = 2; m < 4; ++m) {
                o1[2 * m - 4] = (a[2 * m]     + bf_lo(sv[m])) * inv + b2[f + 2 * m];
                o1[2 * m - 3] = (a[2 * m + 1] + bf_hi(sv[m])) * inv + b2[f + 2 * m + 1];
            }
            *(f32x4*)&out[(size_t)r * F_OUT + f]     = o0;
            *(f32x4*)&out[(size_t)r * F_OUT + f + 4] = o1;
        }
    }
}

// ===========================================================================
// Fallback path (round-11 proven kernels, CAP 96) — used if cooperative
// launch is unavailable / doesn't fit.
// ===========================================================================
__global__ void pre_small_kernel(int* __restrict__ cur, const unsigned* __restrict__ ei,
                                 int* __restrict__ mode) {
    int b = blockIdx.x, t = threadIdx.x;
    if (b < 64) {
        cur[b * 256 + t] = 0;
    } else {
        __shared__ int nz;
        if (t == 0) nz = 0;
        __syncthreads();
        for (int it = 0; it < 4; ++it) {
            int idx = 2 * (t + it * 256) + 1;
            if (ei[idx] != 0u) nz = 1;
        }
        __syncthreads();
        if (t == 0) *mode = (nz == 0) ? 1 : 0;
    }
}

__global__ void prep_fill_kernel(const void* __restrict__ ei, const int* __restrict__ mode,
                                 int* __restrict__ cur, int2* __restrict__ ed, int E, int nF,
                                 const float* __restrict__ x, unsigned short* __restrict__ xb,
                                 const float* __restrict__ W1, unsigned short* __restrict__ W1t,
                                 const float* __restrict__ W2, unsigned short* __restrict__ W2t) {
    int b = blockIdx.x, t = threadIdx.x;
    if (b < nF) {
        int base = b * 1024 + t;
        int m = *mode;
#pragma unroll
        for (int u = 0; u < 4; ++u) {
            int e = base + u * 256;
            if (e >= E) continue;
            int r, c;
            if (m) {
                const long long* p = (const long long*)ei;
                r = (int)p[e]; c = (int)p[e + E];
            } else {
                const int* p = (const int*)ei;
                r = p[e]; c = p[e + E];
            }
            if (((unsigned)r | (unsigned)c) >= N_NODES) continue;
            int pos = atomicAdd(&cur[r], 1);
            if (pos < CAP) ed[r * CAP + pos] = make_int2(c, e);
        }
    } else if (b < nF + 2048) {
        int i = ((b - nF) * 256 + t) * 4;
        float4 v = *(const float4*)&x[i];
        ushort4 o;
        o.x = bf16rne(v.x); o.y = bf16rne(v.y); o.z = bf16rne(v.z); o.w = bf16rne(v.w);
        *(ushort4*)&xb[i] = o;
    } else if (b < nF + 2176) {
        int id = (b - nF - 2048) * 256 + t;
        int n = id >> 7, k = id & 127;
        W1t[id] = bf16rne(W1[(size_t)k * F_HID + n]);
    } else {
        int id = (b - nF - 2176) * 256 + t;
        int n = id >> 8, k = id & 255;
        W2t[id] = bf16rne(W2[(size_t)k * F_OUT + n]);
    }
}

__launch_bounds__(1024, 8)
__global__ void agg_mlp_kernel(const float* __restrict__ ew, int* __restrict__ cur,
                               int2* __restrict__ ed, float* __restrict__ invdeg,
                               const unsigned* __restrict__ xb,
                               const unsigned short* __restrict__ W1t,
                               const unsigned short* __restrict__ W2t,
                               const float* __restrict__ b1,
                               const float* __restrict__ ln_g, const float* __restrict__ ln_b,
                               unsigned short* __restrict__ h2b) {
    __shared__ int   scol[16][CAP];
    __shared__ int   seid[16][CAP];
    __shared__ float sw[16][CAP];
    __shared__ unsigned short H0[16 * H0STR];
    __shared__ unsigned short H1[16 * H1STR];
    __shared__ float red[2][16][16];

    int t = threadIdx.x, wave = t >> 6, lane = t & 63;
    int lnid = lane & 15, quad = lane >> 4;
    int qw = lane >> 4, ql = lane & 15;
    int Rbase = blockIdx.x * 16;
    int r = Rbase + wave;

    int d = cur[r];
    if (d > CAP) d = CAP;
    int dpad = (d + 15) & ~15;
    int2* row = ed + (size_t)r * CAP;
    for (int i = lane; i < d; i += 64) {
        int2 e = row[i];
        scol[wave][i] = e.x;
        seid[wave][i] = e.y;
    }
    for (int i = d + lane; i < dpad; i += 64) {
        scol[wave][i] = -2;
        seid[wave][i] = 0;
    }
    asm volatile("s_waitcnt lgkmcnt(0)" ::: "memory");

    float wsum = 0.0f;
    for (int i = lane; i < d; i += 64) {
        int myc = scol[wave][i], mye = seid[wave][i];
        bool kill = false;
        for (int jb = 0; jb < dpad; jb += 16) KILL16(wave, jb);
        float w = kill ? 0.0f : ew[mye];
        sw[wave][i] = w;
        row[i] = make_int2(myc, __float_as_int(w));
        wsum += w;
    }
    asm volatile("s_waitcnt lgkmcnt(0)" ::: "memory");
    for (int off = 32; off; off >>= 1) wsum += __shfl_xor(wsum, off, 64);
    float inv = 1.0f / (1.0f + wsum);
    if (lane == 0) { invdeg[r] = inv; cur[r] = d; }

    const u32x4* xb4 = (const u32x4*)xb;
    float a[8] = {0, 0, 0, 0, 0, 0, 0, 0};
    QGATHER(wave, xb4, d);
    if (qw == 0) {
        u32x4 sv = xb4[(size_t)r * 16 + ql];
        u32x4 o;
#pragma unroll
        for (int m = 0; m < 4; ++m) {
            float lo = (a[2 * m]     + bf_lo(sv[m])) * inv;
            float hi = (a[2 * m + 1] + bf_hi(sv[m])) * inv;
            o[m] = ((unsigned)bf16rne(hi) << 16) | (unsigned)bf16rne(lo);
        }
        *(u32x4*)&H0[wave * H0STR + ql * 8] = o;
    }
    __syncthreads();

    bf16x8 afr[4];
#pragma unroll
    for (int ch = 0; ch < 4; ++ch)
        afr[ch] = *(const bf16x8*)&H0[lnid * H0STR + ch * 32 + quad * 8];
    f32x4 acc = {0.0f, 0.0f, 0.0f, 0.0f};
    {
        const unsigned short* wrow = &W1t[(size_t)(wave * 16 + lnid) * F_IN];
#pragma unroll
        for (int ch = 0; ch < 4; ++ch) {
            bf16x8 bb = *(const bf16x8*)&wrow[ch * 32 + quad * 8];
            acc = __builtin_amdgcn_mfma_f32_16x16x32_bf16(afr[ch], bb, acc, 0, 0, 0);
        }
    }
    float s[4], q[4];
    {
        float bv = b1[wave * 16 + lnid];
#pragma unroll
        for (int rr = 0; rr < 4; ++rr) {
            float v = acc[rr] + bv;
            acc[rr] = v;
            s[rr] = v; q[rr] = v * v;
        }
    }
#pragma unroll
    for (int rr = 0; rr < 4; ++rr)
        for (int off = 1; off < 16; off <<= 1) {
            s[rr] += __shfl_xor(s[rr], off, 64);
            q[rr] += __shfl_xor(q[rr], off, 64);
        }
    if (lnid == 0) {
#pragma unroll
        for (int rr = 0; rr < 4; ++rr) {
            red[0][wave][quad * 4 + rr] = s[rr];
            red[1][wave][quad * 4 + rr] = q[rr];
        }
    }
    __syncthreads();
    float mean[4], rinv[4];
#pragma unroll
    for (int rr = 0; rr < 4; ++rr) {
        int rowi = quad * 4 + rr;
        float S = 0.0f, Q = 0.0f;
#pragma unroll
        for (int w2 = 0; w2 < 16; ++w2) { S += red[0][w2][rowi]; Q += red[1][w2][rowi]; }
        mean[rr] = S * (1.0f / F_HID);
        float var = Q * (1.0f / F_HID) - mean[rr] * mean[rr];
        rinv[rr] = rsqrtf(var + LN_EPS);
    }
    {
        int c = wave * 16 + lnid;
        float g = ln_g[c], bb = ln_b[c];
#pragma unroll
        for (int rr = 0; rr < 4; ++rr) {
            float v = fmaxf((acc[rr] - mean[rr]) * rinv[rr] * g + bb, 0.0f);
            H1[(quad * 4 + rr) * H1STR + c] = bf16rne(v);
        }
    }
    __syncthreads();

    unsigned short* rep = H0;
    if (wave < 8) {
        bf16x8 a2[8];
#pragma unroll
        for (int ch = 0; ch < 8; ++ch)
            a2[ch] = *(const bf16x8*)&H1[lnid * H1STR + ch * 32 + quad * 8];
        f32x4 c2 = {0.0f, 0.0f, 0.0f, 0.0f};
        const unsigned short* wrow = &W2t[(size_t)(wave * 16 + lnid) * F_HID];
#pragma unroll
        for (int ch = 0; ch < 8; ++ch) {
            bf16x8 bb = *(const bf16x8*)&wrow[ch * 32 + quad * 8];
            c2 = __builtin_amdgcn_mfma_f32_16x16x32_bf16(a2[ch], bb, c2, 0, 0, 0);
        }
#pragma unroll
        for (int rr = 0; rr < 4; ++rr)
            rep[(quad * 4 + rr) * REPSTR + wave * 16 + lnid] = bf16rne(c2[rr]);
    }
    __syncthreads();

    if (t < 512) {
        int m = t >> 5, cgi = t & 31;
        *(ushort4*)&h2b[(size_t)(Rbase + m) * F_OUT + cgi * 4] =
            *(const ushort4*)&rep[m * REPSTR + cgi * 4];
    }
}

__launch_bounds__(1024, 8)
__global__ void spmm2_kernel(const unsigned* __restrict__ xb, const int* __restrict__ cur,
                             const int2* __restrict__ ed, const float* __restrict__ invdeg,
                             const float* __restrict__ bias, float* __restrict__ outp) {
    __shared__ int   scol[16][CAP];
    __shared__ float sw[16][CAP];
    int t = threadIdx.x, wave = t >> 6, lane = t & 63;
    int qw = lane >> 4, ql = lane & 15;
    int r = blockIdx.x * 16 + wave;
    const int2* row = ed + (size_t)r * CAP;
    int d = cur[r];
    if (d > CAP) d = CAP;
    for (int i = lane; i < d; i += 64) {
        int2 e = row[i];
        scol[wave][i] = e.x;
        sw[wave][i] = __int_as_float(e.y);
    }
    asm volatile("s_waitcnt lgkmcnt(0)" ::: "memory");

    const u32x4* xb4 = (const u32x4*)xb;
    float a[8] = {0, 0, 0, 0, 0, 0, 0, 0};
    QGATHER(wave, xb4, d);
    if (qw == 0) {
        float inv = invdeg[r];
        u32x4 sv = xb4[(size_t)r * 16 + ql];
        int f = ql * 8;
        f32x4 o0, o1;
#pragma unroll
        for (int m = 0; m < 2; ++m) {
            o0[2 * m]     = (a[2 * m]     + bf_lo(sv[m])) * inv + bias[f + 2 * m];
            o0[2 * m + 1] = (a[2 * m + 1] + bf_hi(sv[m])) * inv + bias[f + 2 * m + 1];
        }
#pragma unroll
        for (int m = 2; m < 4; ++m) {
            o1[2 * m - 4] = (a[2 * m]     + bf_lo(sv[m])) * inv + bias[f + 2 * m];
            o1[2 * m - 3] = (a[2 * m + 1] + bf_hi(sv[m])) * inv + bias[f + 2 * m + 1];
        }
        *(f32x4*)&outp[(size_t)r * F_OUT + f]     = o0;
        *(f32x4*)&outp[(size_t)r * F_OUT + f + 4] = o1;
    }
}

// ---------------------------------------------------------------------------
extern "C" void kernel_launch(void* const* d_in, const int* in_sizes, int n_in,
                              void* d_out, int out_size, void* d_ws, size_t ws_size,
                              hipStream_t stream) {
    const void*  ei  = d_in[1];
    const float* x   = (const float*)d_in[0];
    const float* ew  = (const float*)d_in[2];
    const float* W1  = (const float*)d_in[3];
    const float* b1  = (const float*)d_in[4];
    const float* W2  = (const float*)d_in[5];
    const float* b2  = (const float*)d_in[6];
    const float* lng = (const float*)d_in[7];
    const float* lnb = (const float*)d_in[8];
    float* out = (float*)d_out;
    int E = in_sizes[2];

    char* w = (char*)d_ws;
    size_t off = 0;
    auto take = [&](size_t bytes) -> char* {
        char* p = w + off;
        off += (bytes + 255) & ~(size_t)255;
        return p;
    };
    int*   cur    = (int*)take((size_t)N_NODES * 4);
    float* invdeg = (float*)take((size_t)N_NODES * 4);
    int2*  ed     = (int2*)take((size_t)N_NODES * CAP * 8);
    unsigned short* xb  = (unsigned short*)take((size_t)N_NODES * F_IN * 2);
    unsigned short* h2b = (unsigned short*)take((size_t)N_NODES * F_OUT * 2);
    unsigned short* W1t = (unsigned short*)take((size_t)F_IN * F_HID * 2);
    unsigned short* W2t = (unsigned short*)take((size_t)F_HID * F_OUT * 2);
    int*   mode   = (int*)take(4);

    // Cooperative mega path: requires 4 co-resident blocks/CU (1024 blocks).
    static int coop = -1;
    if (coop < 0) {
        int nb = 0;
        if (hipOccupancyMaxActiveBlocksPerMultiprocessor(&nb, gcn_mega, NT, 0)
                != hipSuccess)
            nb = 0;
        coop = (nb >= 4) ? 1 : 0;
    }
    if (coop) {
        void* args[] = {(void*)&ei, (void*)&ew, (void*)&x, (void*)&W1, (void*)&b1,
                        (void*)&W2, (void*)&b2, (void*)&lng, (void*)&lnb,
                        (void*)&cur, (void*)&ed, (void*)&xb, (void*)&h2b,
                        (void*)&W1t, (void*)&W2t, (void*)&mode, (void*)&out, (void*)&E};
        hipError_t err = hipLaunchCooperativeKernel((void*)gcn_mega, dim3(NB), dim3(NT),
                                                    args, 0, stream);
        if (err == hipSuccess) return;
        (void)hipGetLastError();   // clear; fall through to the proven path
        coop = 0;
    }

    // Fallback: round-11 proven sequence.
    int nF = (E + 1023) / 1024;
    pre_small_kernel<<<65, 256, 0, stream>>>(cur, (const unsigned*)ei, mode);
    prep_fill_kernel<<<nF + 2304, 256, 0, stream>>>(ei, mode, cur, ed, E, nF,
                                                    x, xb, W1, W1t, W2, W2t);
    agg_mlp_kernel<<<N_NODES / 16, 1024, 0, stream>>>(ew, cur, ed, invdeg,
                                                      (const unsigned*)xb, W1t, W2t,
                                                      b1, lng, lnb, h2b);
    spmm2_kernel<<<N_NODES / 16, 1024, 0, stream>>>((const unsigned*)h2b, cur, ed, invdeg,
                                                    b2, out);
}